// Round 3
// baseline (95.166 us; speedup 1.0000x reference)
//
#include <hip/hip_runtime.h>
#include <math.h>

#define T_DIM 512
#define B_DIM 64
#define D_DIM 256
#define F_DIM 256
#define ALPHA 0.2f
#define L2E 1.44269504089f
#define NEGL -1.0e38f

// workspace layout (floats). Every slot consumed is written the same call.
#define U_OFF 0
#define V_OFF 256
#define P_OFF 512
#define Q_OFF (P_OFF + T_DIM * B_DIM)
#define CI_OFF (Q_OFF + T_DIM * B_DIM)             // ci[3][B][T]
#define GG_OFF (CI_OFF + 3 * B_DIM * T_DIM)        // gg[3][B][T]

__device__ __forceinline__ float lreluf(float x) { return fmaxf(x, ALPHA * x); }

// Kernel A: u = W @ a1, v = W @ a2. One block, 256 threads.
__global__ void k_uv(const float* __restrict__ W, const float* __restrict__ a1,
                     const float* __restrict__ a2, float* __restrict__ ws) {
    __shared__ float s1[F_DIM], s2[F_DIM];
    int tid = threadIdx.x;
    s1[tid] = a1[tid];
    s2[tid] = a2[tid];
    __syncthreads();
    const float4* Wrow = (const float4*)(W + (size_t)tid * F_DIM);
    float acc1 = 0.f, acc2 = 0.f;
    for (int f4 = 0; f4 < F_DIM / 4; ++f4) {
        float4 wv = Wrow[f4];
        int f = f4 * 4;
        acc1 += wv.x * s1[f] + wv.y * s1[f + 1] + wv.z * s1[f + 2] + wv.w * s1[f + 3];
        acc2 += wv.x * s2[f] + wv.y * s2[f + 1] + wv.z * s2[f + 2] + wv.w * s2[f + 3];
    }
    ws[U_OFF + tid] = acc1;
    ws[V_OFF + tid] = acc2;
}

// Kernel B: p[b,t] = x[t,b]·u, q[b,t] = x[t,b]·v. One wave per row r=t*B+b.
__global__ __launch_bounds__(256) void k_pq(const float* __restrict__ x,
                                            const int* __restrict__ turns,
                                            float* __restrict__ ws) {
    __shared__ float su[D_DIM], sv[D_DIM];
    int tid = threadIdx.x;
    su[tid] = ws[U_OFF + tid];
    sv[tid] = ws[V_OFF + tid];
    __syncthreads();
    int wave = tid >> 6, lane = tid & 63;
    int r = blockIdx.x * 4 + wave;
    int t = r >> 6;          // r / B_DIM
    int b = r & 63;          // r % B_DIM
    if (t > turns[b]) return;   // never read downstream (wave-uniform)
    const float4* row = (const float4*)(x + (size_t)r * D_DIM);
    const float4* u4 = (const float4*)su;
    const float4* v4 = (const float4*)sv;
    float4 xv = row[lane];
    float4 uv = u4[lane];
    float4 vv = v4[lane];
    float pp = xv.x * uv.x + xv.y * uv.y + xv.z * uv.z + xv.w * uv.w;
    float qq = xv.x * vv.x + xv.y * vv.y + xv.z * vv.z + xv.w * vv.w;
    for (int off = 32; off > 0; off >>= 1) {
        pp += __shfl_down(pp, off);
        qq += __shfl_down(qq, off);
    }
    if (lane == 0) {
        ws[P_OFF + b * T_DIM + t] = pp;
        ws[Q_OFF + b * T_DIM + t] = qq;
    }
}

// Kernel C1: per (b,w,ichunk) softmax row stats, compressed to
// ci = m_iL + log2(r_i). 768 blocks x 128 threads, log2-domain.
__global__ __launch_bounds__(128) void k_row(const int* __restrict__ turns,
                                             float* __restrict__ ws) {
    int blk = blockIdx.x;
    int b = blk / 12, rem = blk % 12;
    int w = (rem >> 2) + 1, chunk = rem & 3;
    int tn = turns[b];
    int cnt = tn - w + 2;
    if (cnt > T_DIM) cnt = T_DIM;
    if (cnt <= 0) return;                 // window empty: ci never read
    if (chunk * 128 >= cnt) return;       // chunk fully invalid (block-uniform)
    int tid = threadIdx.x;
    __shared__ float sp[T_DIM], sq[T_DIM], f2L[T_DIM];
    __shared__ float red[2];
    ((float4*)sp)[tid] = ((const float4*)(ws + P_OFF + b * T_DIM))[tid];
    ((float4*)sq)[tid] = ((const float4*)(ws + Q_OFF + b * T_DIM))[tid];
    __syncthreads();
    float scale = L2E / (float)w;
    float myf2[4];
    for (int s = 0; s < 4; ++s) {
        int j = tid + s * 128;
        float v;
        if (j < cnt) {
            float a = sq[j];
            for (int k = 1; k < w; ++k) a += sq[j + k];  // j+w-1 <= tn <= 511
            v = a * scale;
        } else {
            v = NEGL;
        }
        f2L[j] = v;
        myf2[s] = v;
    }
    __syncthreads();
    // block max of f2L (valid entries; invalid = NEGL)
    float m = fmaxf(fmaxf(myf2[0], myf2[1]), fmaxf(myf2[2], myf2[3]));
    for (int off = 32; off > 0; off >>= 1) m = fmaxf(m, __shfl_down(m, off));
    if ((tid & 63) == 0) red[tid >> 6] = m;
    __syncthreads();
    float M = fmaxf(red[0], red[1]);
    int i = chunk * 128 + tid;
    if (i < cnt) {
        float a = sp[i];
        for (int k = 1; k < w; ++k) a += sp[i + k];
        float f1 = a * scale;
        float mrow = lreluf(f1 + M);       // analytic row max (lrelu monotone)
        float r = 0.f;
        for (int j = 0; j < cnt; ++j) {
            float s = f1 + f2L[j];
            s = fmaxf(s, ALPHA * s);
            r += __builtin_amdgcn_exp2f(s - mrow);
        }
        ws[CI_OFF + ((w - 1) * B_DIM + b) * T_DIM + i] = mrow + __builtin_amdgcn_logf(r);
    }
}

// Kernel C2: column sums gg[j] = (1/cnt) * sum_i exp2(s_ijL - ci_i).
// 768 blocks x 128 threads; writes all 512 slots per (b,w) across 4 chunks.
__global__ __launch_bounds__(128) void k_col(const int* __restrict__ turns,
                                             float* __restrict__ ws) {
    int blk = blockIdx.x;
    int b = blk / 12, rem = blk % 12;
    int w = (rem >> 2) + 1, chunk = rem & 3;
    int tn = turns[b];
    int cnt = tn - w + 2;
    if (cnt > T_DIM) cnt = T_DIM;
    int tid = threadIdx.x;
    int jj = chunk * 128 + tid;
    float* GG = ws + GG_OFF + ((w - 1) * B_DIM + b) * T_DIM;
    if (cnt <= 0) { GG[jj] = 0.f; return; }            // block-uniform
    if (chunk * 128 >= cnt) { GG[jj] = 0.f; return; }  // block-uniform
    __shared__ float sp[T_DIM], sq[T_DIM];
    __shared__ float2 fc[T_DIM];
    ((float4*)sp)[tid] = ((const float4*)(ws + P_OFF + b * T_DIM))[tid];
    ((float4*)sq)[tid] = ((const float4*)(ws + Q_OFF + b * T_DIM))[tid];
    __syncthreads();
    float scale = L2E / (float)w;
    const float* CI = ws + CI_OFF + ((w - 1) * B_DIM + b) * T_DIM;
    for (int s = 0; s < 4; ++s) {
        int i2 = tid + s * 128;
        float f1 = 0.f, c = 0.f;
        if (i2 < cnt) {
            float a = sp[i2];
            for (int k = 1; k < w; ++k) a += sp[i2 + k];
            f1 = a * scale;
            c = CI[i2];
        }
        fc[i2] = make_float2(f1, c);
    }
    __syncthreads();
    float acc = 0.f;
    if (jj < cnt) {
        float a = sq[jj];
        for (int k = 1; k < w; ++k) a += sq[jj + k];
        float f2 = a * scale;
        for (int i = 0; i < cnt; ++i) {
            float2 t = fc[i];
            float s = t.x + f2;
            s = fmaxf(s, ALPHA * s);
            acc += __builtin_amdgcn_exp2f(s - t.y);
        }
        acc /= (float)cnt;
    }
    GG[jj] = (jj < cnt) ? acc : 0.f;
}

// Kernel D: per-b fused coefficient build + Z = sum_t C[t] x[t,b,:] + out = Z@W/vws.
// 64 blocks x 512 threads.
__global__ __launch_bounds__(512) void k_zo(const float* __restrict__ x,
                                            const int* __restrict__ turns,
                                            const float* __restrict__ W,
                                            const float* __restrict__ ws,
                                            float* __restrict__ out) {
    int b = blockIdx.x;
    int tid = threadIdx.x;
    int tn = turns[b];
    __shared__ float C[T_DIM];
    __shared__ float4 zp[512];
    __shared__ float zz[D_DIM];
    __shared__ float ored[512];
    const float* G1 = ws + GG_OFF + (0 * B_DIM + b) * T_DIM;
    const float* G2 = ws + GG_OFF + (1 * B_DIM + b) * T_DIM;
    const float* G3 = ws + GG_OFF + (2 * B_DIM + b) * T_DIM;
    {
        int t = tid;
        float g2 = G2[t] + (t >= 1 ? G2[t - 1] : 0.f);
        float g3 = G3[t] + (t >= 1 ? G3[t - 1] : 0.f) + (t >= 2 ? G3[t - 2] : 0.f);
        C[t] = G1[t] + 0.5f * g2 + (1.0f / 3.0f) * g3;
    }
    __syncthreads();
    // Z accumulate: 8 t-groups x 64 lanes (float4 over D)
    int lane = tid & 63, g = tid >> 6;
    const float4* x4 = (const float4*)x;
    float4 z = make_float4(0.f, 0.f, 0.f, 0.f);
    int t0 = g * 64, t1 = min(t0 + 64, tn + 1);
    for (int t = t0; t < t1; ++t) {
        float c = C[t];
        float4 xv = x4[((size_t)t * B_DIM + b) * (D_DIM / 4) + lane];
        z.x += c * xv.x; z.y += c * xv.y; z.z += c * xv.z; z.w += c * xv.w;
    }
    zp[tid] = z;
    __syncthreads();
    if (tid < 64) {
        float4 a = zp[tid];
        for (int k = 1; k < 8; ++k) {
            float4 bb = zp[k * 64 + tid];
            a.x += bb.x; a.y += bb.y; a.z += bb.z; a.w += bb.w;
        }
        ((float4*)zz)[tid] = a;
    }
    __syncthreads();
    // out[f] = sum_d zz[d] * W[d,f], split d over 2 halves
    int f = tid & 255, dh = tid >> 8;
    float acc = 0.f;
    for (int d = dh * 128; d < dh * 128 + 128; ++d)
        acc += zz[d] * W[(size_t)d * F_DIM + f];
    ored[tid] = acc;
    __syncthreads();
    if (tid < 256) {
        float vws = 1.f + (tn >= 1 ? 1.f : 0.f) + (tn >= 2 ? 1.f : 0.f);
        out[b * F_DIM + tid] = (ored[tid] + ored[tid + 256]) / vws;
    }
}

extern "C" void kernel_launch(void* const* d_in, const int* in_sizes, int n_in,
                              void* d_out, int out_size, void* d_ws, size_t ws_size,
                              hipStream_t stream) {
    const float* x = (const float*)d_in[0];     // (T,B,D) fp32
    const int* turns = (const int*)d_in[1];     // (B,) int32
    const float* W = (const float*)d_in[2];     // (D,F)
    const float* a1 = (const float*)d_in[3];    // (F,)
    const float* a2 = (const float*)d_in[4];    // (F,)
    float* out = (float*)d_out;                 // (B,F)
    float* ws = (float*)d_ws;

    k_uv<<<1, 256, 0, stream>>>(W, a1, a2, ws);
    k_pq<<<(B_DIM * T_DIM) / 4, 256, 0, stream>>>(x, turns, ws);
    k_row<<<B_DIM * 12, 128, 0, stream>>>(turns, ws);
    k_col<<<B_DIM * 12, 128, 0, stream>>>(turns, ws);
    k_zo<<<B_DIM, 512, 0, stream>>>(x, turns, W, ws, out);
}

// Round 4
// 57.308 us; speedup vs baseline: 1.6606x; 1.6606x over previous
//
#include <hip/hip_runtime.h>
#include <math.h>

#define T_DIM 512
#define B_DIM 64
#define D_DIM 256
#define F_DIM 256
#define ALPHA 0.2f
#define L2E 1.44269504089f
#define NEGL -1.0e38f

// workspace layout (floats). Every slot consumed is written the same call.
#define U_OFF 0
#define V_OFF 256
#define P_OFF 512
#define Q_OFF (P_OFF + T_DIM * B_DIM)
#define CI_OFF (Q_OFF + T_DIM * B_DIM)             // ci[3][B][T]
#define GG_OFF (CI_OFF + 3 * B_DIM * T_DIM)        // gg[3][B][T]
#define ZP_OFF (GG_OFF + 3 * B_DIM * T_DIM)        // Zp[B][16][D]

__device__ __forceinline__ float lreluf(float x) { return fmaxf(x, ALPHA * x); }

// Kernel A: u = W @ a1, v = W @ a2. 64 blocks x 256 thr, one wave per d-row.
__global__ __launch_bounds__(256) void k_uv(const float* __restrict__ W,
                                            const float* __restrict__ a1,
                                            const float* __restrict__ a2,
                                            float* __restrict__ ws) {
    int tid = threadIdx.x;
    int wave = tid >> 6, lane = tid & 63;
    int d = blockIdx.x * 4 + wave;
    float4 wv = ((const float4*)(W + (size_t)d * F_DIM))[lane];
    float4 a1v = ((const float4*)a1)[lane];
    float4 a2v = ((const float4*)a2)[lane];
    float p = wv.x * a1v.x + wv.y * a1v.y + wv.z * a1v.z + wv.w * a1v.w;
    float q = wv.x * a2v.x + wv.y * a2v.y + wv.z * a2v.z + wv.w * a2v.w;
    for (int off = 32; off > 0; off >>= 1) {
        p += __shfl_down(p, off);
        q += __shfl_down(q, off);
    }
    if (lane == 0) {
        ws[U_OFF + d] = p;
        ws[V_OFF + d] = q;
    }
}

// Kernel B: p[b,t] = x[t,b]·u, q[b,t] = x[t,b]·v. One wave per row r=t*B+b.
__global__ __launch_bounds__(256) void k_pq(const float* __restrict__ x,
                                            const int* __restrict__ turns,
                                            float* __restrict__ ws) {
    __shared__ float su[D_DIM], sv[D_DIM];
    int tid = threadIdx.x;
    su[tid] = ws[U_OFF + tid];
    sv[tid] = ws[V_OFF + tid];
    __syncthreads();
    int wave = tid >> 6, lane = tid & 63;
    int r = blockIdx.x * 4 + wave;
    int t = r >> 6;          // r / B_DIM
    int b = r & 63;          // r % B_DIM
    if (t > turns[b]) return;   // never read downstream (wave-uniform)
    const float4* row = (const float4*)(x + (size_t)r * D_DIM);
    const float4* u4 = (const float4*)su;
    const float4* v4 = (const float4*)sv;
    float4 xv = row[lane];
    float4 uv = u4[lane];
    float4 vv = v4[lane];
    float pp = xv.x * uv.x + xv.y * uv.y + xv.z * uv.z + xv.w * uv.w;
    float qq = xv.x * vv.x + xv.y * vv.y + xv.z * vv.z + xv.w * vv.w;
    for (int off = 32; off > 0; off >>= 1) {
        pp += __shfl_down(pp, off);
        qq += __shfl_down(qq, off);
    }
    if (lane == 0) {
        ws[P_OFF + b * T_DIM + t] = pp;
        ws[Q_OFF + b * T_DIM + t] = qq;
    }
}

// Kernel C1: per (b,w,ichunk) softmax row stats, compressed to
// ci = m_iL + log2(r_i). 768 blocks x 128 threads, log2-domain.
__global__ __launch_bounds__(128) void k_row(const int* __restrict__ turns,
                                             float* __restrict__ ws) {
    int blk = blockIdx.x;
    int b = blk / 12, rem = blk % 12;
    int w = (rem >> 2) + 1, chunk = rem & 3;
    int tn = turns[b];
    int cnt = tn - w + 2;
    if (cnt > T_DIM) cnt = T_DIM;
    if (cnt <= 0) return;                 // window empty: ci never read
    if (chunk * 128 >= cnt) return;       // chunk fully invalid (block-uniform)
    int tid = threadIdx.x;
    __shared__ float sp[T_DIM], sq[T_DIM], f2L[T_DIM];
    __shared__ float red[2];
    ((float4*)sp)[tid] = ((const float4*)(ws + P_OFF + b * T_DIM))[tid];
    ((float4*)sq)[tid] = ((const float4*)(ws + Q_OFF + b * T_DIM))[tid];
    __syncthreads();
    float scale = L2E / (float)w;
    float myf2[4];
    for (int s = 0; s < 4; ++s) {
        int j = tid + s * 128;
        float v;
        if (j < cnt) {
            float a = sq[j];
            for (int k = 1; k < w; ++k) a += sq[j + k];  // j+w-1 <= tn <= 511
            v = a * scale;
        } else {
            v = NEGL;
        }
        f2L[j] = v;
        myf2[s] = v;
    }
    __syncthreads();
    // block max of f2L (valid entries; invalid = NEGL)
    float m = fmaxf(fmaxf(myf2[0], myf2[1]), fmaxf(myf2[2], myf2[3]));
    for (int off = 32; off > 0; off >>= 1) m = fmaxf(m, __shfl_down(m, off));
    if ((tid & 63) == 0) red[tid >> 6] = m;
    __syncthreads();
    float M = fmaxf(red[0], red[1]);
    int i = chunk * 128 + tid;
    if (i < cnt) {
        float a = sp[i];
        for (int k = 1; k < w; ++k) a += sp[i + k];
        float f1 = a * scale;
        float mrow = lreluf(f1 + M);       // analytic row max (lrelu monotone)
        float r = 0.f;
        for (int j = 0; j < cnt; ++j) {
            float s = f1 + f2L[j];
            s = fmaxf(s, ALPHA * s);
            r += __builtin_amdgcn_exp2f(s - mrow);
        }
        ws[CI_OFF + ((w - 1) * B_DIM + b) * T_DIM + i] = mrow + __builtin_amdgcn_logf(r);
    }
}

// Kernel C2: column sums gg[j] = (1/cnt) * sum_i exp2(s_ijL - ci_i).
// 768 blocks x 128 threads; writes all 512 slots per (b,w) across 4 chunks.
__global__ __launch_bounds__(128) void k_col(const int* __restrict__ turns,
                                             float* __restrict__ ws) {
    int blk = blockIdx.x;
    int b = blk / 12, rem = blk % 12;
    int w = (rem >> 2) + 1, chunk = rem & 3;
    int tn = turns[b];
    int cnt = tn - w + 2;
    if (cnt > T_DIM) cnt = T_DIM;
    int tid = threadIdx.x;
    int jj = chunk * 128 + tid;
    float* GG = ws + GG_OFF + ((w - 1) * B_DIM + b) * T_DIM;
    if (cnt <= 0) { GG[jj] = 0.f; return; }            // block-uniform
    if (chunk * 128 >= cnt) { GG[jj] = 0.f; return; }  // block-uniform
    __shared__ float sp[T_DIM], sq[T_DIM];
    __shared__ float2 fc[T_DIM];
    ((float4*)sp)[tid] = ((const float4*)(ws + P_OFF + b * T_DIM))[tid];
    ((float4*)sq)[tid] = ((const float4*)(ws + Q_OFF + b * T_DIM))[tid];
    __syncthreads();
    float scale = L2E / (float)w;
    const float* CI = ws + CI_OFF + ((w - 1) * B_DIM + b) * T_DIM;
    for (int s = 0; s < 4; ++s) {
        int i2 = tid + s * 128;
        float f1 = 0.f, c = 0.f;
        if (i2 < cnt) {
            float a = sp[i2];
            for (int k = 1; k < w; ++k) a += sp[i2 + k];
            f1 = a * scale;
            c = CI[i2];
        }
        fc[i2] = make_float2(f1, c);
    }
    __syncthreads();
    float acc = 0.f;
    if (jj < cnt) {
        float a = sq[jj];
        for (int k = 1; k < w; ++k) a += sq[jj + k];
        float f2 = a * scale;
        for (int i = 0; i < cnt; ++i) {
            float2 t = fc[i];
            float s = t.x + f2;
            s = fmaxf(s, ALPHA * s);
            acc += __builtin_amdgcn_exp2f(s - t.y);
        }
        acc /= (float)cnt;
    }
    GG[jj] = (jj < cnt) ? acc : 0.f;
}

// Kernel D: Zp[b][chunk][d] = sum_{t in chunk of 32} C[b,t] * x[t,b,d].
// 1024 blocks (64 b x 16 chunks) x 256 thr; 4 wave-groups x 8 t, full unroll.
__global__ __launch_bounds__(256) void k_z(const float* __restrict__ x,
                                           const int* __restrict__ turns,
                                           float* __restrict__ ws) {
    int b = blockIdx.x >> 4;
    int chunk = blockIdx.x & 15;
    int tn = turns[b];
    int tid = threadIdx.x;
    int lane = tid & 63, g = tid >> 6;
    int t0b = chunk * 32;
    __shared__ float Cs[32];
    __shared__ float4 zp[256];
    float4 z = make_float4(0.f, 0.f, 0.f, 0.f);
    if (t0b <= tn) {  // block-uniform
        if (tid < 32) {
            int t = t0b + tid;
            const float* G1 = ws + GG_OFF + (0 * B_DIM + b) * T_DIM;
            const float* G2 = ws + GG_OFF + (1 * B_DIM + b) * T_DIM;
            const float* G3 = ws + GG_OFF + (2 * B_DIM + b) * T_DIM;
            // GG is zero beyond each window's cnt, so C[t] = 0 for t > tn.
            float g2 = G2[t] + (t >= 1 ? G2[t - 1] : 0.f);
            float g3 = G3[t] + (t >= 1 ? G3[t - 1] : 0.f) + (t >= 2 ? G3[t - 2] : 0.f);
            Cs[tid] = G1[t] + 0.5f * g2 + (1.0f / 3.0f) * g3;
        }
        __syncthreads();
        const float4* x4 = (const float4*)x;
        int tg = t0b + g * 8;
        size_t base = ((size_t)tg * B_DIM + b) * (D_DIM / 4) + lane;
#pragma unroll
        for (int tt = 0; tt < 8; ++tt) {
            float c = Cs[g * 8 + tt];
            float4 xv = x4[base + (size_t)tt * (B_DIM * D_DIM / 4)];
            z.x += c * xv.x; z.y += c * xv.y; z.z += c * xv.z; z.w += c * xv.w;
        }
    }
    zp[tid] = z;
    __syncthreads();
    if (tid < 64) {
        float4 a = zp[tid];
        float4 b1 = zp[64 + tid], c1 = zp[128 + tid], d1 = zp[192 + tid];
        a.x += b1.x + c1.x + d1.x;
        a.y += b1.y + c1.y + d1.y;
        a.z += b1.z + c1.z + d1.z;
        a.w += b1.w + c1.w + d1.w;
        ((float4*)(ws + ZP_OFF + (b * 16 + chunk) * D_DIM))[tid] = a;
    }
}

// Kernel E: out[b,:] = ((sum_chunk Zp[b][chunk]) @ W) / vws[b]. 64 blocks x 512 thr.
__global__ __launch_bounds__(512) void k_out(const float* __restrict__ W,
                                             const int* __restrict__ turns,
                                             const float* __restrict__ ws,
                                             float* __restrict__ out) {
    int b = blockIdx.x;
    int tid = threadIdx.x;
    __shared__ float zhalf[2][D_DIM];
    __shared__ float zz[D_DIM];
    __shared__ float ored[512];
    int d = tid & 255, half = tid >> 8;
    const float* Zp = ws + ZP_OFF + b * 16 * D_DIM;
    float a = 0.f;
#pragma unroll
    for (int s = 0; s < 8; ++s) a += Zp[(half * 8 + s) * D_DIM + d];
    zhalf[half][d] = a;
    __syncthreads();
    if (tid < 256) zz[tid] = zhalf[0][tid] + zhalf[1][tid];
    __syncthreads();
    float acc = 0.f;
    int f = tid & 255, dh = tid >> 8;
#pragma unroll 8
    for (int dd = dh * 128; dd < dh * 128 + 128; ++dd)
        acc += zz[dd] * W[(size_t)dd * F_DIM + f];
    ored[tid] = acc;
    __syncthreads();
    if (tid < 256) {
        int tn = turns[b];
        float vws = 1.f + (tn >= 1 ? 1.f : 0.f) + (tn >= 2 ? 1.f : 0.f);
        out[b * F_DIM + tid] = (ored[tid] + ored[tid + 256]) / vws;
    }
}

extern "C" void kernel_launch(void* const* d_in, const int* in_sizes, int n_in,
                              void* d_out, int out_size, void* d_ws, size_t ws_size,
                              hipStream_t stream) {
    const float* x = (const float*)d_in[0];     // (T,B,D) fp32
    const int* turns = (const int*)d_in[1];     // (B,) int32
    const float* W = (const float*)d_in[2];     // (D,F)
    const float* a1 = (const float*)d_in[3];    // (F,)
    const float* a2 = (const float*)d_in[4];    // (F,)
    float* out = (float*)d_out;                 // (B,F)
    float* ws = (float*)d_ws;

    k_uv<<<B_DIM, 256, 0, stream>>>(W, a1, a2, ws);
    k_pq<<<(B_DIM * T_DIM) / 4, 256, 0, stream>>>(x, turns, ws);
    k_row<<<B_DIM * 12, 128, 0, stream>>>(turns, ws);
    k_col<<<B_DIM * 12, 128, 0, stream>>>(turns, ws);
    k_z<<<B_DIM * 16, 256, 0, stream>>>(x, turns, ws);
    k_out<<<B_DIM, 512, 0, stream>>>(W, turns, ws, out);
}